// Round 12
// baseline (635.205 us; speedup 1.0000x reference)
//
#include <hip/hip_runtime.h>
#include <hip/hip_bf16.h>

#define NNODES 10000
#define NB 8
#define NF 128
#define NE 160000
#define NGRP 2500   // 4-node work items per batch (one node per wave)

typedef __attribute__((ext_vector_type(8))) short  short8;   // 8 bf16 (A/B frag)
typedef __attribute__((ext_vector_type(8))) unsigned short ushort8;
typedef __attribute__((ext_vector_type(4))) float  f32x4;    // MFMA acc

// s_getreg encoding: id | offset<<6 | (size-1)<<11 ; HW_REG_XCC_ID = 20 (verified R11:
// agg FETCH collapsed 144->15.7 MB once claims were XCD-pinned)
#define HWREG_XCC_ID (20 | (0 << 6) | ((4 - 1) << 11))

// fp32 -> bf16 (RNE) scalar
__device__ __forceinline__ unsigned short f2b(float f) {
    union { float f; unsigned u; } v; v.f = f;
    unsigned r = v.u + 0x7FFF + ((v.u >> 16) & 1);
    return (unsigned short)(r >> 16);
}
// packed pair fp32 -> bf16x2 (v_cvt_pk_bf16_f32)
__device__ __forceinline__ unsigned int f2b2(float a, float b) {
    union { __hip_bfloat162 h; unsigned int u; } v;
    v.h = __float22bfloat162_rn(make_float2(a, b));
    return v.u;
}
__device__ __forceinline__ float b2f_lo(unsigned u) {
    union { unsigned u; float f; } v; v.u = u << 16; return v.f;
}
__device__ __forceinline__ float b2f_hi(unsigned u) {
    union { unsigned u; float f; } v; v.u = u & 0xffff0000u; return v.f;
}

// ---------------- preprocessing ----------------

// blocks 0..624: degree count; blocks 625..752: W->Wt bf16 transpose (independent)
__global__ void k_count_wt(const int* __restrict__ ei, int* __restrict__ cnt,
                           const float* __restrict__ W1, unsigned short* __restrict__ Wt1,
                           const float* __restrict__ W2, unsigned short* __restrict__ Wt2) {
    int bid = blockIdx.x;
    if (bid < 625) {
        int e = bid * 256 + threadIdx.x;           // NE = 625*256 exactly
        atomicAdd(&cnt[ei[NE + e]], 1);
    } else {
        int id2 = (bid - 625) * 256 + threadIdx.x; // 0..32767
        const float* W = (id2 < 16384) ? W1 : W2;
        unsigned short* Wt = (id2 < 16384) ? Wt1 : Wt2;
        int id = id2 & 16383;
        int n = id >> 7, k = id & 127;
        Wt[n * 128 + k] = f2b(W[k * 128 + n]);
    }
}

// one-block scan of cnt -> row_ptr (+ dinv); wave-shuffle based, 2 barriers
__global__ __launch_bounds__(1024) void k_scan(const int* __restrict__ cnt,
                                               int* __restrict__ row_ptr,
                                               float* __restrict__ dinv) {
    __shared__ int wsum[16];
    const int t = threadIdx.x;
    const int lane = t & 63, wv = t >> 6;
    const int CH = 10;                       // 1024*10 >= NNODES
    int lo = t * CH;
    int hi = min(lo + CH, NNODES);
    int c10[CH];
    int s = 0;
    for (int i = lo; i < hi; i++) {
        int c = cnt[i];
        c10[i - lo] = c;
        dinv[i] = rsqrtf((float)(c + 1));
        s += c;
    }
    int v = s;                               // inclusive scan within wave
    #pragma unroll
    for (int m = 1; m < 64; m <<= 1) {
        int o = __shfl_up(v, m);
        if (lane >= m) v += o;
    }
    if (lane == 63) wsum[wv] = v;
    __syncthreads();
    if (t < 16) {
        int w = wsum[t];
        #pragma unroll
        for (int m = 1; m < 16; m <<= 1) {
            int o = __shfl_up(w, m);
            if (t >= m) w += o;
        }
        wsum[t] = w;
    }
    __syncthreads();
    int base = v - s + (wv ? wsum[wv - 1] : 0);
    for (int i = lo; i < hi; i++) { row_ptr[i] = base; base += c10[i - lo]; }
    if (t == 1023) row_ptr[NNODES] = wsum[15];
}

// CSR scatter; edge[pos] = src(16b) | bf16(w) << 16   (4 B per edge)
__global__ void k_scatter(const int* __restrict__ ei, const int* __restrict__ row_ptr,
                          int* __restrict__ fill, const float* __restrict__ dinv,
                          unsigned int* __restrict__ edge) {
    int e = blockIdx.x * blockDim.x + threadIdx.x;
    if (e >= NE) return;
    int s = ei[e];
    int d = ei[NE + e];
    int pos = row_ptr[d] + atomicAdd(&fill[d], 1);
    edge[pos] = (unsigned)s | ((unsigned)f2b(dinv[s] * dinv[d]) << 16);
}

// ---------------- bf16 MFMA matmul ----------------
// C = A[80000,128] @ W, bf16 out row gm -> Cn + gm*128 ([B,N,128] order).
// A-op fragments (Wt, 32 KB shared by all blocks) loaded directly from global
// (L1/L2-resident). LDS only for the coalesced C write-out.
template <bool ABF16>
__global__ __launch_bounds__(256) void k_mm_mfma(const void* __restrict__ Ap,
                                                 const unsigned short* __restrict__ Wt,
                                                 unsigned short* __restrict__ Cn) {
    __shared__ unsigned short clds[128 * 136];  // C-stage only (34.8 KB)
    const int t = threadIdx.x;
    const int wid = t >> 6, lane = t & 63;
    const int quad = lane >> 4, l16 = lane & 15;
    const int m0 = blockIdx.x * 128 + (wid & 1) * 64;  // act row base for this wave
    const int nb = (wid >> 1) * 64;                    // feature base
    const int kq = quad * 8;

    f32x4 acc[4][4] = {};

    #pragma unroll
    for (int ks = 0; ks < 128; ks += 32) {
        short8 af[4];
        #pragma unroll
        for (int ni = 0; ni < 4; ni++)
            af[ni] = *(const short8*)(Wt + (size_t)(nb + ni * 16 + l16) * 128 + ks + kq);
        short8 bf[4];
        #pragma unroll
        for (int mi = 0; mi < 4; mi++) {
            const size_t row = (size_t)(m0 + mi * 16 + l16);
            if constexpr (ABF16) {
                bf[mi] = *(const short8*)((const unsigned short*)Ap + row * 128 + ks + kq);
            } else {
                const float* p = (const float*)Ap + row * 128 + ks + kq;
                float4 u0 = *(const float4*)p;
                float4 u1 = *(const float4*)(p + 4);
                union { uint4 u4; short8 s8; } cv;
                cv.u4.x = f2b2(u0.x, u0.y); cv.u4.y = f2b2(u0.z, u0.w);
                cv.u4.z = f2b2(u1.x, u1.y); cv.u4.w = f2b2(u1.z, u1.w);
                bf[mi] = cv.s8;
            }
        }
        #pragma unroll
        for (int mi = 0; mi < 4; mi++)
            #pragma unroll
            for (int ni = 0; ni < 4; ni++)
                acc[mi][ni] = __builtin_amdgcn_mfma_f32_16x16x32_bf16(
                    af[ni], bf[mi], acc[mi][ni], 0, 0, 0);
    }

    {
        const int rbase = (wid & 1) * 64;
        #pragma unroll
        for (int mi = 0; mi < 4; mi++) {
            int rr = rbase + mi * 16 + l16;
            #pragma unroll
            for (int ni = 0; ni < 4; ni++) {
                uint2 p;
                p.x = f2b2(acc[mi][ni][0], acc[mi][ni][1]);
                p.y = f2b2(acc[mi][ni][2], acc[mi][ni][3]);
                *(uint2*)(clds + rr * 136 + nb + ni * 16 + quad * 4) = p;
            }
        }
    }
    __syncthreads();
    {
        const int r = t >> 1, h = t & 1;     // 128 rows x 2 halves of 128 B
        size_t gm = (size_t)blockIdx.x * 128 + r;
        unsigned short* dst = Cn + gm * 128 + h * 64;
        const unsigned short* srow = clds + r * 136 + h * 64;
        #pragma unroll
        for (int i = 0; i < 8; i++)
            *(ushort8*)(dst + i * 8) = *(const ushort8*)(srow + i * 8);
    }
}

// ---------------- aggregation ----------------
// hNu: bf16 [B, N, 128] viewed as uint. Work item = (batch, 4-node group);
// ONE NODE PER WAVE (R11's 4-nodes-per-wave q-loop cost 4x TLP -> latency-
// exposed). Block claims an item for batch b = its actual XCD id
// (HW_REG_XCC_ID), stealing from other batches when drained (correctness
// never depends on the id). Pins batch b's contiguous 2.56 MB slice +
// 0.64 MB edges in that XCD's 4 MB L2 (verified: FETCH 144->15.7 MB).

__device__ __forceinline__ int claim_item(int* ctr) {
    int xcc = __builtin_amdgcn_s_getreg(HWREG_XCC_ID) & 7;
    int got = -1;
    for (int k = 0; k < 8; k++) {
        int b = (xcc + k) & 7;
        int idx = atomicAdd(&ctr[b], 1);
        if (idx < NGRP) { got = b * NGRP + idx; break; }
    }
    return got;
}

__global__ __launch_bounds__(256) void k_agg_relu(const unsigned int* __restrict__ hNu,
                                                  const float* __restrict__ bias,
                                                  const int* __restrict__ row_ptr,
                                                  const unsigned int* __restrict__ edge,
                                                  const float* __restrict__ dinv,
                                                  unsigned int* __restrict__ h1u,
                                                  int* __restrict__ ctr) {
    __shared__ int s_item;
    if (threadIdx.x == 0) s_item = claim_item(ctr);
    __syncthreads();
    const int item = s_item;
    if (item < 0) return;
    const int b = item / NGRP;
    const int g = item - b * NGRP;
    const int wid = __builtin_amdgcn_readfirstlane(threadIdx.x >> 6);
    const int lane = threadIdx.x & 63;
    const int n = g * 4 + wid;

    const unsigned int* base = hNu + (size_t)b * NNODES * 64 + lane;  // + s*64
    float di = dinv[n];
    float wself = di * di;
    unsigned int u = base[(size_t)n * 64];
    float a0 = b2f_lo(u) * wself;
    float a1 = b2f_hi(u) * wself;

    int e = row_ptr[n], e1 = row_ptr[n + 1];
    for (; e + 8 <= e1; e += 8) {
        unsigned int E[8];
        #pragma unroll
        for (int j = 0; j < 8; j++) E[j] = edge[e + j];
        unsigned int U[8];
        #pragma unroll
        for (int j = 0; j < 8; j++) U[j] = base[(size_t)(E[j] & 0xffffu) * 64];
        #pragma unroll
        for (int j = 0; j < 8; j++) {
            float w = b2f_hi(E[j]);
            a0 = fmaf(b2f_lo(U[j]), w, a0);
            a1 = fmaf(b2f_hi(U[j]), w, a1);
        }
    }
    for (; e + 4 <= e1; e += 4) {
        unsigned int E[4];
        #pragma unroll
        for (int j = 0; j < 4; j++) E[j] = edge[e + j];
        unsigned int U[4];
        #pragma unroll
        for (int j = 0; j < 4; j++) U[j] = base[(size_t)(E[j] & 0xffffu) * 64];
        #pragma unroll
        for (int j = 0; j < 4; j++) {
            float w = b2f_hi(E[j]);
            a0 = fmaf(b2f_lo(U[j]), w, a0);
            a1 = fmaf(b2f_hi(U[j]), w, a1);
        }
    }
    for (; e < e1; ++e) {
        unsigned int E = edge[e];
        float w = b2f_hi(E);
        unsigned int uu = base[(size_t)(E & 0xffffu) * 64];
        a0 = fmaf(b2f_lo(uu), w, a0);
        a1 = fmaf(b2f_hi(uu), w, a1);
    }
    a0 = fmaxf(a0 + bias[lane * 2], 0.f);
    a1 = fmaxf(a1 + bias[lane * 2 + 1], 0.f);
    __builtin_nontemporal_store(f2b2(a0, a1), &h1u[((size_t)b * NNODES + n) * 64 + lane]);
}

__global__ __launch_bounds__(256) void k_agg_ln(const unsigned int* __restrict__ hNu,
                                                const float* __restrict__ bias,
                                                const int* __restrict__ row_ptr,
                                                const unsigned int* __restrict__ edge,
                                                const float* __restrict__ dinv,
                                                const float* __restrict__ ln_w,
                                                const float* __restrict__ ln_b,
                                                float* __restrict__ out,
                                                int* __restrict__ ctr) {
    __shared__ int s_item;
    if (threadIdx.x == 0) s_item = claim_item(ctr);
    __syncthreads();
    const int item = s_item;
    if (item < 0) return;
    const int b = item / NGRP;
    const int g = item - b * NGRP;
    const int wid = __builtin_amdgcn_readfirstlane(threadIdx.x >> 6);
    const int lane = threadIdx.x & 63;
    const int n = g * 4 + wid;

    const unsigned int* base = hNu + (size_t)b * NNODES * 64 + lane;
    float di = dinv[n];
    float wself = di * di;
    unsigned int u = base[(size_t)n * 64];
    float a0 = b2f_lo(u) * wself;
    float a1 = b2f_hi(u) * wself;

    int e = row_ptr[n], e1 = row_ptr[n + 1];
    for (; e + 8 <= e1; e += 8) {
        unsigned int E[8];
        #pragma unroll
        for (int j = 0; j < 8; j++) E[j] = edge[e + j];
        unsigned int U[8];
        #pragma unroll
        for (int j = 0; j < 8; j++) U[j] = base[(size_t)(E[j] & 0xffffu) * 64];
        #pragma unroll
        for (int j = 0; j < 8; j++) {
            float w = b2f_hi(E[j]);
            a0 = fmaf(b2f_lo(U[j]), w, a0);
            a1 = fmaf(b2f_hi(U[j]), w, a1);
        }
    }
    for (; e + 4 <= e1; e += 4) {
        unsigned int E[4];
        #pragma unroll
        for (int j = 0; j < 4; j++) E[j] = edge[e + j];
        unsigned int U[4];
        #pragma unroll
        for (int j = 0; j < 4; j++) U[j] = base[(size_t)(E[j] & 0xffffu) * 64];
        #pragma unroll
        for (int j = 0; j < 4; j++) {
            float w = b2f_hi(E[j]);
            a0 = fmaf(b2f_lo(U[j]), w, a0);
            a1 = fmaf(b2f_hi(U[j]), w, a1);
        }
    }
    for (; e < e1; ++e) {
        unsigned int E = edge[e];
        float w = b2f_hi(E);
        unsigned int uu = base[(size_t)(E & 0xffffu) * 64];
        a0 = fmaf(b2f_lo(uu), w, a0);
        a1 = fmaf(b2f_hi(uu), w, a1);
    }
    a0 += bias[lane * 2];
    a1 += bias[lane * 2 + 1];

    // LayerNorm over 128 feats spread across the 64-lane wave (2/lane)
    float s1 = a0 + a1;
    float s2 = a0 * a0 + a1 * a1;
    #pragma unroll
    for (int m = 1; m < 64; m <<= 1) {
        s1 += __shfl_xor(s1, m);
        s2 += __shfl_xor(s2, m);
    }
    float mu = s1 * (1.f / NF);
    float var = s2 * (1.f / NF) - mu * mu;
    float rs = rsqrtf(var + 1e-5f);

    float o0 = (a0 - mu) * rs * ln_w[lane * 2] + ln_b[lane * 2];
    float o1 = (a1 - mu) * rs * ln_w[lane * 2 + 1] + ln_b[lane * 2 + 1];
    float* dst = out + ((size_t)b * NNODES + n) * 128 + lane * 2;
    __builtin_nontemporal_store(o0, dst);
    __builtin_nontemporal_store(o1, dst + 1);
}

// ---------------- launch ----------------

extern "C" void kernel_launch(void* const* d_in, const int* in_sizes, int n_in,
                              void* d_out, int out_size, void* d_ws, size_t ws_size,
                              hipStream_t stream) {
    const float* x    = (const float*)d_in[0];
    const int*   ei   = (const int*)d_in[1];   // int32 [2, E]
    const float* W1   = (const float*)d_in[2];
    const float* b1   = (const float*)d_in[3];
    const float* W2   = (const float*)d_in[4];
    const float* b2   = (const float*)d_in[5];
    const float* ln_w = (const float*)d_in[6];
    const float* ln_b = (const float*)d_in[7];
    float* out = (float*)d_out;

    // workspace layout (no aliasing)
    char* ws = (char*)d_ws;
    int*            cnt     = (int*)(ws + 0);          // 40192
    int*            fill    = (int*)(ws + 40192);      // 40192
    int*            ctrA    = (int*)(ws + 80384);      // 8 ints (agg1 work counters)
    int*            ctrB    = (int*)(ws + 80416);      // 8 ints (agg2)
    int*            row_ptr = (int*)(ws + 80448);      // 40064
    float*          dinv    = (float*)(ws + 120512);   // 40000
    unsigned int*   edge    = (unsigned int*)(ws + 160512);     // 640000
    unsigned short* Wt1     = (unsigned short*)(ws + 800512);   // 32768
    unsigned short* Wt2     = (unsigned short*)(ws + 833280);   // 32768
    unsigned short* hA16    = (unsigned short*)(ws + 1441024);  // [B,N,128] bf16 (20.48 MB)
    unsigned short* h1b     = (unsigned short*)(ws + 21921024); // [B,N,128] bf16 (20.48 MB)

    // ---- CSR (by dst) + norm weights + bf16 weights ----
    hipMemsetAsync(ws, 0, 80448, stream);              // cnt + fill + ctrA/B
    k_count_wt<<<753, 256, 0, stream>>>(ei, cnt, W1, Wt1, W2, Wt2);
    k_scan    <<<1, 1024, 0, stream>>>(cnt, row_ptr, dinv);
    k_scatter <<<(NE + 255) / 256, 256, 0, stream>>>(ei, row_ptr, fill, dinv, edge);

    // ---- layer 1 ----
    k_mm_mfma<false><<<(NB * NNODES) / 128, 256, 0, stream>>>(x, Wt1, hA16);
    k_agg_relu<<<NB * NGRP, 256, 0, stream>>>((const unsigned int*)hA16, b1,
                                              row_ptr, edge, dinv,
                                              (unsigned int*)h1b, ctrA);

    // ---- layer 2 ----
    k_mm_mfma<true><<<(NB * NNODES) / 128, 256, 0, stream>>>(h1b, Wt2, hA16);
    k_agg_ln<<<NB * NGRP, 256, 0, stream>>>((const unsigned int*)hA16, b2,
                                            row_ptr, edge, dinv,
                                            ln_w, ln_b, out, ctrB);
}

// Round 13
// 233.082 us; speedup vs baseline: 2.7252x; 2.7252x over previous
//
#include <hip/hip_runtime.h>
#include <hip/hip_bf16.h>

#define NNODES 10000
#define NB 8
#define NF 128
#define NE 160000
#define CHUNK 40            // nodes per work item (one claim per block)
#define NGRP (NNODES / CHUNK)   // 250 items per batch

typedef __attribute__((ext_vector_type(8))) short  short8;   // 8 bf16 (A/B frag)
typedef __attribute__((ext_vector_type(8))) unsigned short ushort8;
typedef __attribute__((ext_vector_type(4))) float  f32x4;    // MFMA acc

// s_getreg encoding: id | offset<<6 | (size-1)<<11 ; HW_REG_XCC_ID = 20 (verified R11:
// agg FETCH collapsed 144->15.7 MB once claims were XCD-pinned)
#define HWREG_XCC_ID (20 | (0 << 6) | ((4 - 1) << 11))

// fp32 -> bf16 (RNE) scalar
__device__ __forceinline__ unsigned short f2b(float f) {
    union { float f; unsigned u; } v; v.f = f;
    unsigned r = v.u + 0x7FFF + ((v.u >> 16) & 1);
    return (unsigned short)(r >> 16);
}
// packed pair fp32 -> bf16x2 (v_cvt_pk_bf16_f32)
__device__ __forceinline__ unsigned int f2b2(float a, float b) {
    union { __hip_bfloat162 h; unsigned int u; } v;
    v.h = __float22bfloat162_rn(make_float2(a, b));
    return v.u;
}
__device__ __forceinline__ float b2f_lo(unsigned u) {
    union { unsigned u; float f; } v; v.u = u << 16; return v.f;
}
__device__ __forceinline__ float b2f_hi(unsigned u) {
    union { unsigned u; float f; } v; v.u = u & 0xffff0000u; return v.f;
}

// ---------------- preprocessing ----------------

// blocks 0..624: degree count; blocks 625..752: W->Wt bf16 transpose (independent)
__global__ void k_count_wt(const int* __restrict__ ei, int* __restrict__ cnt,
                           const float* __restrict__ W1, unsigned short* __restrict__ Wt1,
                           const float* __restrict__ W2, unsigned short* __restrict__ Wt2) {
    int bid = blockIdx.x;
    if (bid < 625) {
        int e = bid * 256 + threadIdx.x;           // NE = 625*256 exactly
        atomicAdd(&cnt[ei[NE + e]], 1);
    } else {
        int id2 = (bid - 625) * 256 + threadIdx.x; // 0..32767
        const float* W = (id2 < 16384) ? W1 : W2;
        unsigned short* Wt = (id2 < 16384) ? Wt1 : Wt2;
        int id = id2 & 16383;
        int n = id >> 7, k = id & 127;
        Wt[n * 128 + k] = f2b(W[k * 128 + n]);
    }
}

// one-block scan of cnt -> row_ptr (+ dinv); wave-shuffle based, 2 barriers
__global__ __launch_bounds__(1024) void k_scan(const int* __restrict__ cnt,
                                               int* __restrict__ row_ptr,
                                               float* __restrict__ dinv) {
    __shared__ int wsum[16];
    const int t = threadIdx.x;
    const int lane = t & 63, wv = t >> 6;
    const int CH = 10;                       // 1024*10 >= NNODES
    int lo = t * CH;
    int hi = min(lo + CH, NNODES);
    int c10[CH];
    int s = 0;
    for (int i = lo; i < hi; i++) {
        int c = cnt[i];
        c10[i - lo] = c;
        dinv[i] = rsqrtf((float)(c + 1));
        s += c;
    }
    int v = s;                               // inclusive scan within wave
    #pragma unroll
    for (int m = 1; m < 64; m <<= 1) {
        int o = __shfl_up(v, m);
        if (lane >= m) v += o;
    }
    if (lane == 63) wsum[wv] = v;
    __syncthreads();
    if (t < 16) {
        int w = wsum[t];
        #pragma unroll
        for (int m = 1; m < 16; m <<= 1) {
            int o = __shfl_up(w, m);
            if (t >= m) w += o;
        }
        wsum[t] = w;
    }
    __syncthreads();
    int base = v - s + (wv ? wsum[wv - 1] : 0);
    for (int i = lo; i < hi; i++) { row_ptr[i] = base; base += c10[i - lo]; }
    if (t == 1023) row_ptr[NNODES] = wsum[15];
}

// CSR scatter; edge[pos] = src(16b) | bf16(w) << 16   (4 B per edge)
__global__ void k_scatter(const int* __restrict__ ei, const int* __restrict__ row_ptr,
                          int* __restrict__ fill, const float* __restrict__ dinv,
                          unsigned int* __restrict__ edge) {
    int e = blockIdx.x * blockDim.x + threadIdx.x;
    if (e >= NE) return;
    int s = ei[e];
    int d = ei[NE + e];
    int pos = row_ptr[d] + atomicAdd(&fill[d], 1);
    edge[pos] = (unsigned)s | ((unsigned)f2b(dinv[s] * dinv[d]) << 16);
}

// ---------------- bf16 MFMA matmul ----------------
// C = A[80000,128] @ W, bf16 out row gm -> Cn + gm*128 ([B,N,128] order).
// A-op fragments (Wt, 32 KB shared by all blocks) loaded directly from global
// (L1/L2-resident). LDS only for the coalesced C write-out.
template <bool ABF16>
__global__ __launch_bounds__(256) void k_mm_mfma(const void* __restrict__ Ap,
                                                 const unsigned short* __restrict__ Wt,
                                                 unsigned short* __restrict__ Cn) {
    __shared__ unsigned short clds[128 * 136];  // C-stage only (34.8 KB)
    const int t = threadIdx.x;
    const int wid = t >> 6, lane = t & 63;
    const int quad = lane >> 4, l16 = lane & 15;
    const int m0 = blockIdx.x * 128 + (wid & 1) * 64;  // act row base for this wave
    const int nb = (wid >> 1) * 64;                    // feature base
    const int kq = quad * 8;

    f32x4 acc[4][4] = {};

    #pragma unroll
    for (int ks = 0; ks < 128; ks += 32) {
        short8 af[4];
        #pragma unroll
        for (int ni = 0; ni < 4; ni++)
            af[ni] = *(const short8*)(Wt + (size_t)(nb + ni * 16 + l16) * 128 + ks + kq);
        short8 bf[4];
        #pragma unroll
        for (int mi = 0; mi < 4; mi++) {
            const size_t row = (size_t)(m0 + mi * 16 + l16);
            if constexpr (ABF16) {
                bf[mi] = *(const short8*)((const unsigned short*)Ap + row * 128 + ks + kq);
            } else {
                const float* p = (const float*)Ap + row * 128 + ks + kq;
                float4 u0 = *(const float4*)p;
                float4 u1 = *(const float4*)(p + 4);
                union { uint4 u4; short8 s8; } cv;
                cv.u4.x = f2b2(u0.x, u0.y); cv.u4.y = f2b2(u0.z, u0.w);
                cv.u4.z = f2b2(u1.x, u1.y); cv.u4.w = f2b2(u1.z, u1.w);
                bf[mi] = cv.s8;
            }
        }
        #pragma unroll
        for (int mi = 0; mi < 4; mi++)
            #pragma unroll
            for (int ni = 0; ni < 4; ni++)
                acc[mi][ni] = __builtin_amdgcn_mfma_f32_16x16x32_bf16(
                    af[ni], bf[mi], acc[mi][ni], 0, 0, 0);
    }

    {
        const int rbase = (wid & 1) * 64;
        #pragma unroll
        for (int mi = 0; mi < 4; mi++) {
            int rr = rbase + mi * 16 + l16;
            #pragma unroll
            for (int ni = 0; ni < 4; ni++) {
                uint2 p;
                p.x = f2b2(acc[mi][ni][0], acc[mi][ni][1]);
                p.y = f2b2(acc[mi][ni][2], acc[mi][ni][3]);
                *(uint2*)(clds + rr * 136 + nb + ni * 16 + quad * 4) = p;
            }
        }
    }
    __syncthreads();
    {
        const int r = t >> 1, h = t & 1;     // 128 rows x 2 halves of 128 B
        size_t gm = (size_t)blockIdx.x * 128 + r;
        unsigned short* dst = Cn + gm * 128 + h * 64;
        const unsigned short* srow = clds + r * 136 + h * 64;
        #pragma unroll
        for (int i = 0; i < 8; i++)
            *(ushort8*)(dst + i * 8) = *(const ushort8*)(srow + i * 8);
    }
}

// ---------------- aggregation ----------------
// hNu: bf16 [B, N, 128] viewed as uint. Work item = (batch, 40-node chunk);
// ONE claim per block (2000 total, was 20000 in R12 -> 233 us: all 8 counters
// shared one cache line, cross-XCD atomic ping-pong). Counters now padded to
// 256 B each; contention is same-XCD only, 250 claims/counter.
// Block = 4 waves; wave wid processes nodes chunk+wid, +4, ... (10 nodes),
// one node per wave at a time; lane holds feats {2*lane, 2*lane+1}.
// Batch b = block's actual XCD id (HW_REG_XCC_ID), stealing when drained
// (correct regardless of id). Pins batch b's contiguous 2.56 MB slice +
// 0.64 MB edges in that XCD's 4 MB L2 (verified: FETCH 144->15.7 MB).

__device__ __forceinline__ int claim_item(int* ctr) {
    int xcc = __builtin_amdgcn_s_getreg(HWREG_XCC_ID) & 7;
    int got = -1;
    for (int k = 0; k < 8; k++) {
        int b = (xcc + k) & 7;
        int idx = atomicAdd(&ctr[b * 64], 1);    // 256-B padded counters
        if (idx < NGRP) { got = b * NGRP + idx; break; }
    }
    return got;
}

__global__ __launch_bounds__(256) void k_agg_relu(const unsigned int* __restrict__ hNu,
                                                  const float* __restrict__ bias,
                                                  const int* __restrict__ row_ptr,
                                                  const unsigned int* __restrict__ edge,
                                                  const float* __restrict__ dinv,
                                                  unsigned int* __restrict__ h1u,
                                                  int* __restrict__ ctr) {
    __shared__ int s_item;
    if (threadIdx.x == 0) s_item = claim_item(ctr);
    __syncthreads();
    const int item = s_item;
    if (item < 0) return;
    const int b = item / NGRP;
    const int g = item - b * NGRP;
    const int wid = __builtin_amdgcn_readfirstlane(threadIdx.x >> 6);
    const int lane = threadIdx.x & 63;

    const unsigned int* base = hNu + (size_t)b * NNODES * 64 + lane;  // + s*64
    const float bias0 = bias[lane * 2], bias1 = bias[lane * 2 + 1];

    for (int q = 0; q < CHUNK / 4; q++) {
        const int n = g * CHUNK + wid + q * 4;
        float di = dinv[n];
        float wself = di * di;
        unsigned int u = base[(size_t)n * 64];
        float a0 = b2f_lo(u) * wself;
        float a1 = b2f_hi(u) * wself;

        int e = row_ptr[n], e1 = row_ptr[n + 1];
        for (; e + 8 <= e1; e += 8) {
            unsigned int E[8];
            #pragma unroll
            for (int j = 0; j < 8; j++) E[j] = edge[e + j];
            unsigned int U[8];
            #pragma unroll
            for (int j = 0; j < 8; j++) U[j] = base[(size_t)(E[j] & 0xffffu) * 64];
            #pragma unroll
            for (int j = 0; j < 8; j++) {
                float w = b2f_hi(E[j]);
                a0 = fmaf(b2f_lo(U[j]), w, a0);
                a1 = fmaf(b2f_hi(U[j]), w, a1);
            }
        }
        for (; e + 4 <= e1; e += 4) {
            unsigned int E[4];
            #pragma unroll
            for (int j = 0; j < 4; j++) E[j] = edge[e + j];
            unsigned int U[4];
            #pragma unroll
            for (int j = 0; j < 4; j++) U[j] = base[(size_t)(E[j] & 0xffffu) * 64];
            #pragma unroll
            for (int j = 0; j < 4; j++) {
                float w = b2f_hi(E[j]);
                a0 = fmaf(b2f_lo(U[j]), w, a0);
                a1 = fmaf(b2f_hi(U[j]), w, a1);
            }
        }
        for (; e < e1; ++e) {
            unsigned int E = edge[e];
            float w = b2f_hi(E);
            unsigned int uu = base[(size_t)(E & 0xffffu) * 64];
            a0 = fmaf(b2f_lo(uu), w, a0);
            a1 = fmaf(b2f_hi(uu), w, a1);
        }
        float r0 = fmaxf(a0 + bias0, 0.f);
        float r1 = fmaxf(a1 + bias1, 0.f);
        __builtin_nontemporal_store(f2b2(r0, r1),
                                    &h1u[((size_t)b * NNODES + n) * 64 + lane]);
    }
}

__global__ __launch_bounds__(256) void k_agg_ln(const unsigned int* __restrict__ hNu,
                                                const float* __restrict__ bias,
                                                const int* __restrict__ row_ptr,
                                                const unsigned int* __restrict__ edge,
                                                const float* __restrict__ dinv,
                                                const float* __restrict__ ln_w,
                                                const float* __restrict__ ln_b,
                                                float* __restrict__ out,
                                                int* __restrict__ ctr) {
    __shared__ int s_item;
    if (threadIdx.x == 0) s_item = claim_item(ctr);
    __syncthreads();
    const int item = s_item;
    if (item < 0) return;
    const int b = item / NGRP;
    const int g = item - b * NGRP;
    const int wid = __builtin_amdgcn_readfirstlane(threadIdx.x >> 6);
    const int lane = threadIdx.x & 63;

    const unsigned int* base = hNu + (size_t)b * NNODES * 64 + lane;
    const float bias0 = bias[lane * 2], bias1 = bias[lane * 2 + 1];
    const float lnw0 = ln_w[lane * 2], lnw1 = ln_w[lane * 2 + 1];
    const float lnb0 = ln_b[lane * 2], lnb1 = ln_b[lane * 2 + 1];

    for (int q = 0; q < CHUNK / 4; q++) {
        const int n = g * CHUNK + wid + q * 4;
        float di = dinv[n];
        float wself = di * di;
        unsigned int u = base[(size_t)n * 64];
        float a0 = b2f_lo(u) * wself;
        float a1 = b2f_hi(u) * wself;

        int e = row_ptr[n], e1 = row_ptr[n + 1];
        for (; e + 8 <= e1; e += 8) {
            unsigned int E[8];
            #pragma unroll
            for (int j = 0; j < 8; j++) E[j] = edge[e + j];
            unsigned int U[8];
            #pragma unroll
            for (int j = 0; j < 8; j++) U[j] = base[(size_t)(E[j] & 0xffffu) * 64];
            #pragma unroll
            for (int j = 0; j < 8; j++) {
                float w = b2f_hi(E[j]);
                a0 = fmaf(b2f_lo(U[j]), w, a0);
                a1 = fmaf(b2f_hi(U[j]), w, a1);
            }
        }
        for (; e + 4 <= e1; e += 4) {
            unsigned int E[4];
            #pragma unroll
            for (int j = 0; j < 4; j++) E[j] = edge[e + j];
            unsigned int U[4];
            #pragma unroll
            for (int j = 0; j < 4; j++) U[j] = base[(size_t)(E[j] & 0xffffu) * 64];
            #pragma unroll
            for (int j = 0; j < 4; j++) {
                float w = b2f_hi(E[j]);
                a0 = fmaf(b2f_lo(U[j]), w, a0);
                a1 = fmaf(b2f_hi(U[j]), w, a1);
            }
        }
        for (; e < e1; ++e) {
            unsigned int E = edge[e];
            float w = b2f_hi(E);
            unsigned int uu = base[(size_t)(E & 0xffffu) * 64];
            a0 = fmaf(b2f_lo(uu), w, a0);
            a1 = fmaf(b2f_hi(uu), w, a1);
        }
        a0 += bias0;
        a1 += bias1;

        // LayerNorm over 128 feats spread across the 64-lane wave (2/lane)
        float s1 = a0 + a1;
        float s2 = a0 * a0 + a1 * a1;
        #pragma unroll
        for (int m = 1; m < 64; m <<= 1) {
            s1 += __shfl_xor(s1, m);
            s2 += __shfl_xor(s2, m);
        }
        float mu = s1 * (1.f / NF);
        float var = s2 * (1.f / NF) - mu * mu;
        float rs = rsqrtf(var + 1e-5f);

        float o0 = (a0 - mu) * rs * lnw0 + lnb0;
        float o1 = (a1 - mu) * rs * lnw1 + lnb1;
        float* dst = out + ((size_t)b * NNODES + n) * 128 + lane * 2;
        __builtin_nontemporal_store(o0, dst);
        __builtin_nontemporal_store(o1, dst + 1);
    }
}

// ---------------- launch ----------------

extern "C" void kernel_launch(void* const* d_in, const int* in_sizes, int n_in,
                              void* d_out, int out_size, void* d_ws, size_t ws_size,
                              hipStream_t stream) {
    const float* x    = (const float*)d_in[0];
    const int*   ei   = (const int*)d_in[1];   // int32 [2, E]
    const float* W1   = (const float*)d_in[2];
    const float* b1   = (const float*)d_in[3];
    const float* W2   = (const float*)d_in[4];
    const float* b2   = (const float*)d_in[5];
    const float* ln_w = (const float*)d_in[6];
    const float* ln_b = (const float*)d_in[7];
    float* out = (float*)d_out;

    // workspace layout (no aliasing); counters padded to 256 B/line
    char* ws = (char*)d_ws;
    int*            cnt     = (int*)(ws + 0);          // 40192
    int*            fill    = (int*)(ws + 40192);      // 40192
    int*            ctrA    = (int*)(ws + 80384);      // 8 x 256 B
    int*            ctrB    = (int*)(ws + 82432);      // 8 x 256 B
    int*            row_ptr = (int*)(ws + 84480);      // 40064
    float*          dinv    = (float*)(ws + 124544);   // 40000
    unsigned int*   edge    = (unsigned int*)(ws + 164544);     // 640000
    unsigned short* Wt1     = (unsigned short*)(ws + 804544);   // 32768
    unsigned short* Wt2     = (unsigned short*)(ws + 837312);   // 32768
    unsigned short* hA16    = (unsigned short*)(ws + 1441024);  // [B,N,128] bf16 (20.48 MB)
    unsigned short* h1b     = (unsigned short*)(ws + 21921024); // [B,N,128] bf16 (20.48 MB)

    // ---- CSR (by dst) + norm weights + bf16 weights ----
    hipMemsetAsync(ws, 0, 84480, stream);              // cnt + fill + ctrA/B
    k_count_wt<<<753, 256, 0, stream>>>(ei, cnt, W1, Wt1, W2, Wt2);
    k_scan    <<<1, 1024, 0, stream>>>(cnt, row_ptr, dinv);
    k_scatter <<<(NE + 255) / 256, 256, 0, stream>>>(ei, row_ptr, fill, dinv, edge);

    // ---- layer 1 ----
    k_mm_mfma<false><<<(NB * NNODES) / 128, 256, 0, stream>>>(x, Wt1, hA16);
    k_agg_relu<<<NB * NGRP, 256, 0, stream>>>((const unsigned int*)hA16, b1,
                                              row_ptr, edge, dinv,
                                              (unsigned int*)h1b, ctrA);

    // ---- layer 2 ----
    k_mm_mfma<true><<<(NB * NNODES) / 128, 256, 0, stream>>>(h1b, Wt2, hA16);
    k_agg_ln<<<NB * NGRP, 256, 0, stream>>>((const unsigned int*)hA16, b2,
                                            row_ptr, edge, dinv,
                                            ln_w, ln_b, out, ctrB);
}